// Round 12
// baseline (163.367 us; speedup 1.0000x reference)
//
#include <hip/hip_runtime.h>

#define NB 32
#define NC 1024
#define NT 512
#define NO 1024
#define KTILES 48   // 3072 / 64

typedef __attribute__((ext_vector_type(8))) short bf16x8;
typedef __attribute__((ext_vector_type(4))) float f32x4;

#define FENCE asm volatile("" ::: "memory")
#define BAR do{ FENCE; __builtin_amdgcn_s_barrier(); FENCE; }while(0)
#define LGKM0 asm volatile("s_waitcnt lgkmcnt(0)" ::: "memory")

__device__ __forceinline__ unsigned short f2bf(float f){
  unsigned int i = __float_as_uint(f);
  i += 0x7fffu + ((i >> 16) & 1u);
  return (unsigned short)(i >> 16);
}

__device__ __forceinline__ unsigned int blend_pack(unsigned int u0, unsigned int u1, float t){
  float a0 = __uint_as_float(u0 << 16);
  float a1 = __uint_as_float(u0 & 0xffff0000u);
  float b0 = __uint_as_float(u1 << 16);
  float b1 = __uint_as_float(u1 & 0xffff0000u);
  float r0 = fmaf(t, b0 - a0, a0);
  float r1 = fmaf(t, b1 - a1, a1);
  return (unsigned int)f2bf(r0) | (((unsigned int)f2bf(r1)) << 16);
}

__device__ __forceinline__ void async16(const void* g, void* l){
  __builtin_amdgcn_global_load_lds((const __attribute__((address_space(1))) void*)g,
                                   (__attribute__((address_space(3))) void*)l, 16, 0, 0);
}

// ---- merged prep: bid<4096 -> transpose+offset-conv partials (float4 x-loads);
//      bid>=4096 -> wmix (verified body). Tile layout: main cols 4..67 (16B-aligned,
//      stride 72 floats = 288B = 18x16B), left halo [3], right halo [68].
__global__ __launch_bounds__(256) void prep_kernel(const float* __restrict__ x,
    const float* __restrict__ w_off, const float* __restrict__ w_conv,
    unsigned short* __restrict__ atr, float* __restrict__ part,
    unsigned short* __restrict__ wm2){
  __shared__ float tile[64][72];
  __shared__ float wsh[64][9];
  __shared__ float red[4][64][3];
  int bid = blockIdx.x;
  if (bid < 4096){
    int bx = bid & 7, by = (bid >> 3) & 15, bz = bid >> 7;
    int b = bz, c0 = by * 64, t0 = bx * 64;
    int tx = threadIdx.x & 63, wy = threadIdx.x >> 6;
    const float* xp = x + ((size_t)b * NC + c0) * NT + t0;
    int p4 = threadIdx.x & 15, rr = threadIdx.x >> 4;   // 16 rows per pass
    #pragma unroll
    for (int i = 0; i < 4; i++){
      int cl = i * 16 + rr;
      *(float4*)&tile[cl][4 + p4 * 4] = *(const float4*)&xp[(size_t)cl * NT + p4 * 4];
    }
    if (threadIdx.x < 64){
      tile[threadIdx.x][3]  = (t0 > 0)       ? xp[(size_t)threadIdx.x * NT - 1]  : 0.f;
    } else if (threadIdx.x < 128){
      int c = threadIdx.x - 64;
      tile[c][68] = (t0 + 64 < NT) ? xp[(size_t)c * NT + 64] : 0.f;
    }
    for (int i = threadIdx.x; i < 576; i += 256){
      int c = i / 9, r = i % 9;
      wsh[c][r] = w_off[(size_t)(r / 3) * 3072 + (size_t)(c0 + c) * 3 + (r % 3)];
    }
    __syncthreads();
    int p = threadIdx.x & 31, r2 = threadIdx.x >> 5;
    unsigned int* dst = (unsigned int*)(atr + ((size_t)b * NT + t0) * NC + c0);
    #pragma unroll
    for (int i = 0; i < 8; i++){
      int tl = r2 * 8 + i;
      unsigned int lo = f2bf(tile[2 * p][4 + tl]);
      unsigned int hi = f2bf(tile[2 * p + 1][4 + tl]);
      dst[(size_t)tl * (NC / 2) + p] = lo | (hi << 16);
    }
    float s0 = 0.f, s1 = 0.f, s2 = 0.f;
    #pragma unroll 4
    for (int i = 0; i < 16; i++){
      int c = wy * 16 + i;
      float xm = tile[c][3 + tx], xc = tile[c][4 + tx], xq = tile[c][5 + tx];
      s0 += xm * wsh[c][0] + xc * wsh[c][1] + xq * wsh[c][2];
      s1 += xm * wsh[c][3] + xc * wsh[c][4] + xq * wsh[c][5];
      s2 += xm * wsh[c][6] + xc * wsh[c][7] + xq * wsh[c][8];
    }
    red[wy][tx][0] = s0; red[wy][tx][1] = s1; red[wy][tx][2] = s2;
    __syncthreads();
    if (threadIdx.x < 192){
      int tl = threadIdx.x & 63, o = threadIdx.x >> 6;
      float v = red[0][tl][o] + red[1][tl][o] + red[2][tl][o] + red[3][tl][o];
      size_t m = (size_t)b * NT + t0 + tl;
      part[(m * 3 + o) * 16 + by] = v;
    }
  } else {
    int gid = (bid - 4096) * 256 + threadIdx.x;
    int o = gid >> 10, c = gid & 1023;
    const float ratio = (float)(1024.0 / 1023.0);
    float acc0 = 0.f, acc1 = 0.f, acc2 = 0.f;
    int wlo = (c > 2) ? c - 2 : 0;
    int whi = (c < 1021) ? c + 2 : 1023;
    for (int w = wlo; w <= whi; ++w){
      float px = (float)w * ratio - 0.5f;
      float x0 = floorf(px);
      float tx = px - x0;
      int i0 = (int)x0;
      int i0c = min(max(i0, 0), 1023);
      int i1c = min(max(i0 + 1, 0), 1023);
      float s = ((i0c == c) ? (1.0f - tx) : 0.f) + ((i1c == c) ? tx : 0.f);
      if (s != 0.f){
        const float* wc = w_conv + ((size_t)o * 1024 + w) * 3;
        acc0 += s * wc[0]; acc1 += s * wc[1]; acc2 += s * wc[2];
      }
    }
    size_t base = (size_t)o * 3072 + c;
    wm2[base]        = f2bf(acc0);
    wm2[base + 1024] = f2bf(acc1);
    wm2[base + 2048] = f2bf(acc2);
  }
}

// ---- blend + inlined index math: 4 rows/block, 32B/thread, 12 loads up-front ----
__global__ __launch_bounds__(256) void blend_kernel(
    const unsigned short* __restrict__ atr, const float* __restrict__ part,
    const float* __restrict__ b_off, unsigned short* __restrict__ Abl){
  __shared__ int si0[4][3], si1[4][3];
  __shared__ float sty[4][3];
  int row0 = blockIdx.x * 4;
  if (threadIdx.x < 12){
    int lr = (int)threadIdx.x / 3, o = (int)threadIdx.x % 3;
    int row = row0 + lr;
    int gid = row * 3 + o;
    const float4* pp = (const float4*)(part + (size_t)gid * 16);
    float4 pa = pp[0], pb = pp[1], pc = pp[2], pd = pp[3];
    float p = b_off[o] + (((pa.x + pa.y) + (pa.z + pa.w)) + ((pb.x + pb.y) + (pb.z + pb.w)))
                       + (((pc.x + pc.y) + (pc.z + pc.w)) + ((pd.x + pd.y) + (pd.z + pd.w)));
    int tt = row & 511;
    float base = (float)tt / 511.0f * 2.0f - 1.0f;
    float g = base + (float)(o - 1) * (float)(2.0 / 511.0) + p;
    g = fminf(1.0f, fmaxf(-1.0f, g));
    float py = ((g + 1.0f) * 512.0f - 1.0f) * 0.5f;
    float y0 = floorf(py);
    int i0 = (int)y0;
    si0[lr][o] = min(max(i0, 0), NT - 1);
    si1[lr][o] = min(max(i0 + 1, 0), NT - 1);
    sty[lr][o] = py - y0;
  }
  __syncthreads();
  int lr = threadIdx.x >> 6;
  int row = row0 + lr;
  int seg = threadIdx.x & 63;      // 32B units: 64 threads cover a 2KB row
  int b = row >> 9;
  const unsigned short* base = atr + (size_t)b * NT * NC + (size_t)seg * 16;
  unsigned short* orow = Abl + (size_t)row * 3072 + (size_t)seg * 16;
  uint4 v0[6], v1[6]; float t[3];
  #pragma unroll
  for (int k = 0; k < 3; k++){
    const uint4* r0 = (const uint4*)(base + (size_t)si0[lr][k] * NC);
    const uint4* r1 = (const uint4*)(base + (size_t)si1[lr][k] * NC);
    v0[2 * k] = r0[0]; v0[2 * k + 1] = r0[1];
    v1[2 * k] = r1[0]; v1[2 * k + 1] = r1[1];
    t[k] = sty[lr][k];
  }
  #pragma unroll
  for (int k = 0; k < 3; k++)
    #pragma unroll
    for (int h = 0; h < 2; h++){
      uint4 a = v0[2 * k + h], c = v1[2 * k + h], rv;
      rv.x = blend_pack(a.x, c.x, t[k]);
      rv.y = blend_pack(a.y, c.y, t[k]);
      rv.z = blend_pack(a.z, c.z, t[k]);
      rv.w = blend_pack(a.w, c.w, t[k]);
      *(uint4*)(orow + k * 1024 + h * 8) = rv;
    }
}

// ---- stage one 128x64 half-tile via global_load_lds, inverse-swizzled source ----
__device__ __forceinline__ void stage_half(const unsigned short* __restrict__ src,
                                           unsigned short* Lbase, int row0, int q,
                                           int w, int lane){
  int l3 = lane >> 3, l7 = lane & 7;
  int swc = ((l7 ^ l3) << 3);
  #pragma unroll
  for (int i = 0; i < 2; i++){
    int ci = i * 8 + w;
    const unsigned short* g = src + (size_t)(row0 + ci * 8 + l3) * 3072 + q * 64 + swc;
    async16(g, Lbase + ci * 512);
  }
}

// ---- 256x256 8-phase GEMM (frozen loop) + LDS-coalesced epilogue (round-11) ----
__global__ __launch_bounds__(512, 2) void gemm8_kernel(
    const unsigned short* __restrict__ A, const unsigned short* __restrict__ Bw,
    const float* __restrict__ b_conv, float* __restrict__ out){
  __shared__ __align__(16) unsigned short L[65536];

  int wg = blockIdx.x;
  int swz = (wg & 7) * 32 + (wg >> 3);
  int mtile = swz >> 2, ntile = swz & 3;
  int m0 = mtile * 256, n0 = ntile * 256;
  int tid = threadIdx.x, lane = tid & 63, w = tid >> 6;
  int wm_ = w >> 2, wn_ = w & 3;
  int lq = lane & 15, q4 = lane >> 4;
  int sl0 = (q4 ^ (lq & 7)) << 3;
  int sl1 = ((4 + q4) ^ (lq & 7)) << 3;
  int hb = wn_ >> 1, nb = (wn_ & 1) * 64;

  f32x4 acc[8][4];
  #pragma unroll
  for (int i = 0; i < 8; i++)
    #pragma unroll
    for (int j = 0; j < 4; j++) acc[i][j] = (f32x4){0.f, 0.f, 0.f, 0.f};

  // prologue: tile0 (A0,A1,B0,B1) + tile1 (B0,B1); vmcnt(4) drains tile0, leaves B(1)
  stage_half(A,  &L[0],                 m0,       0, w, lane);
  stage_half(A,  &L[8192],              m0 + 128, 0, w, lane);
  stage_half(Bw, &L[16384],             n0,       0, w, lane);
  stage_half(Bw, &L[16384 + 8192],      n0 + 128, 0, w, lane);
  stage_half(Bw, &L[32768 + 16384],        n0,       1, w, lane);
  stage_half(Bw, &L[32768 + 16384 + 8192], n0 + 128, 1, w, lane);
  asm volatile("s_waitcnt vmcnt(4)" ::: "memory");
  BAR;

  bf16x8 aA[4][2], bB[4][2];

  for (int t = 0; t < KTILES; ++t){
    int c = (t & 1) * 32768;
    int cn = ((t + 1) & 1) * 32768;
    const unsigned short* LA = &L[c + wm_ * 8192];
    const unsigned short* LB = &L[c + 16384 + hb * 8192];

    // ---- P1: read A(mh0) + B(nf0,1); stage A(t+1,h0); MFMA(mh0,np0)
    #pragma unroll
    for (int mf = 0; mf < 4; mf++){
      int r = mf * 16 + lq;
      aA[mf][0] = *(const bf16x8*)&LA[r * 64 + sl0];
      aA[mf][1] = *(const bf16x8*)&LA[r * 64 + sl1];
    }
    #pragma unroll
    for (int nf = 0; nf < 2; nf++){
      int r = nb + nf * 16 + lq;
      bB[nf][0] = *(const bf16x8*)&LB[r * 64 + sl0];
      bB[nf][1] = *(const bf16x8*)&LB[r * 64 + sl1];
    }
    if (t + 1 < KTILES) stage_half(A, &L[cn], m0, t + 1, w, lane);
    BAR; LGKM0;
    __builtin_amdgcn_s_setprio(1);
    #pragma unroll
    for (int mf = 0; mf < 4; mf++)
      #pragma unroll
      for (int nf = 0; nf < 2; nf++){
        acc[mf][nf] = __builtin_amdgcn_mfma_f32_16x16x32_bf16(aA[mf][0], bB[nf][0], acc[mf][nf], 0, 0, 0);
        acc[mf][nf] = __builtin_amdgcn_mfma_f32_16x16x32_bf16(aA[mf][1], bB[nf][1], acc[mf][nf], 0, 0, 0);
      }
    __builtin_amdgcn_s_setprio(0);
    BAR;

    // ---- P2: read B(nf2,3); stage A(t+1,h1); MFMA(mh0,np1)
    #pragma unroll
    for (int nf = 2; nf < 4; nf++){
      int r = nb + nf * 16 + lq;
      bB[nf][0] = *(const bf16x8*)&LB[r * 64 + sl0];
      bB[nf][1] = *(const bf16x8*)&LB[r * 64 + sl1];
    }
    if (t + 1 < KTILES) stage_half(A, &L[cn + 8192], m0 + 128, t + 1, w, lane);
    BAR; LGKM0;
    __builtin_amdgcn_s_setprio(1);
    #pragma unroll
    for (int mf = 0; mf < 4; mf++)
      #pragma unroll
      for (int nf = 2; nf < 4; nf++){
        acc[mf][nf] = __builtin_amdgcn_mfma_f32_16x16x32_bf16(aA[mf][0], bB[nf][0], acc[mf][nf], 0, 0, 0);
        acc[mf][nf] = __builtin_amdgcn_mfma_f32_16x16x32_bf16(aA[mf][1], bB[nf][1], acc[mf][nf], 0, 0, 0);
      }
    __builtin_amdgcn_s_setprio(0);
    BAR;

    // ---- P3: read A(mh1); stage B(t+2,h0); MFMA(mh1,np1)
    #pragma unroll
    for (int mf = 0; mf < 4; mf++){
      int r = 64 + mf * 16 + lq;
      aA[mf][0] = *(const bf16x8*)&LA[r * 64 + sl0];
      aA[mf][1] = *(const bf16x8*)&LA[r * 64 + sl1];
    }
    if (t + 2 < KTILES) stage_half(Bw, &L[c + 16384], n0, t + 2, w, lane);
    BAR; LGKM0;
    __builtin_amdgcn_s_setprio(1);
    #pragma unroll
    for (int mf = 0; mf < 4; mf++)
      #pragma unroll
      for (int nf = 2; nf < 4; nf++){
        acc[4 + mf][nf] = __builtin_amdgcn_mfma_f32_16x16x32_bf16(aA[mf][0], bB[nf][0], acc[4 + mf][nf], 0, 0, 0);
        acc[4 + mf][nf] = __builtin_amdgcn_mfma_f32_16x16x32_bf16(aA[mf][1], bB[nf][1], acc[4 + mf][nf], 0, 0, 0);
      }
    __builtin_amdgcn_s_setprio(0);
    BAR;

    // ---- P4: stage B(t+2,h1); MFMA(mh1,np0); boundary counted vmcnt
    if (t + 2 < KTILES) stage_half(Bw, &L[c + 16384 + 8192], n0 + 128, t + 2, w, lane);
    BAR;
    __builtin_amdgcn_s_setprio(1);
    #pragma unroll
    for (int mf = 0; mf < 4; mf++)
      #pragma unroll
      for (int nf = 0; nf < 2; nf++){
        acc[4 + mf][nf] = __builtin_amdgcn_mfma_f32_16x16x32_bf16(aA[mf][0], bB[nf][0], acc[4 + mf][nf], 0, 0, 0);
        acc[4 + mf][nf] = __builtin_amdgcn_mfma_f32_16x16x32_bf16(aA[mf][1], bB[nf][1], acc[4 + mf][nf], 0, 0, 0);
      }
    __builtin_amdgcn_s_setprio(0);
    if (t + 2 < KTILES)      { asm volatile("s_waitcnt vmcnt(4)" ::: "memory"); }
    else if (t + 1 < KTILES) { asm volatile("s_waitcnt vmcnt(0)" ::: "memory"); }
    BAR;
  }

  // ---- epilogue: LDS-coalesced store (per-wave [16][68] f32 tile, bias fused)
  {
    float* Lf = (float*)L;
    float* wt = Lf + w * 1088;
    float bcv[4];
    #pragma unroll
    for (int nf = 0; nf < 4; nf++) bcv[nf] = b_conv[n0 + wn_ * 64 + nf * 16 + lq];
    int ncol = n0 + wn_ * 64 + lq * 4;
    #pragma unroll
    for (int mh = 0; mh < 2; mh++)
      #pragma unroll
      for (int mf = 0; mf < 4; mf++){
        #pragma unroll
        for (int nf = 0; nf < 4; nf++){
          f32x4 v = acc[mh * 4 + mf][nf];
          #pragma unroll
          for (int j = 0; j < 4; j++)
            wt[(q4 * 4 + j) * 68 + nf * 16 + lq] = v[j] + bcv[nf];
        }
        LGKM0;
        int mrow0 = m0 + wm_ * 128 + mh * 64 + mf * 16;
        #pragma unroll
        for (int r = 0; r < 4; r++){
          f32x4 v = *(const f32x4*)&wt[(r * 4 + q4) * 68 + lq * 4];
          *(f32x4*)&out[(size_t)(mrow0 + r * 4 + q4) * NO + ncol] = v;
        }
        LGKM0;
      }
  }
}

extern "C" void kernel_launch(void* const* d_in, const int* in_sizes, int n_in,
                              void* d_out, int out_size, void* d_ws, size_t ws_size,
                              hipStream_t stream){
  (void)in_sizes; (void)n_in; (void)out_size; (void)ws_size;
  const float* x      = (const float*)d_in[0];
  const float* w_off  = (const float*)d_in[1];
  const float* b_off  = (const float*)d_in[2];
  const float* w_conv = (const float*)d_in[3];
  const float* b_conv = (const float*)d_in[4];
  float* out = (float*)d_out;

  char* ws = (char*)d_ws;
  unsigned short* atr = (unsigned short*)ws;                        // 32 MB  (B,T,C) bf16
  float* part = (float*)(ws + 33554432);                            // 3 MB
  unsigned short* wm2 = (unsigned short*)(ws + 37289984);           // 6 MB
  unsigned short* Abl = (unsigned short*)(ws + 43581440);           // 96 MB (proven layout)

  hipLaunchKernelGGL(prep_kernel,  dim3(8192), dim3(256), 0, stream,
                     x, w_off, w_conv, atr, part, wm2);
  hipLaunchKernelGGL(blend_kernel, dim3(16384 / 4), dim3(256), 0, stream,
                     atr, part, b_off, Abl);
  hipLaunchKernelGGL(gemm8_kernel, dim3((16384 / 256) * (1024 / 256)), dim3(512), 0, stream,
                     Abl, wm2, b_conv, out);
}

// Round 13
// 158.016 us; speedup vs baseline: 1.0339x; 1.0339x over previous
//
#include <hip/hip_runtime.h>

#define NB 32
#define NC 1024
#define NT 512
#define NO 1024
#define KTILES 48   // 3072 / 64

typedef __attribute__((ext_vector_type(8))) short bf16x8;
typedef __attribute__((ext_vector_type(4))) float f32x4;

#define FENCE asm volatile("" ::: "memory")
#define BAR do{ FENCE; __builtin_amdgcn_s_barrier(); FENCE; }while(0)
#define LGKM0 asm volatile("s_waitcnt lgkmcnt(0)" ::: "memory")

__device__ __forceinline__ unsigned short f2bf(float f){
  unsigned int i = __float_as_uint(f);
  i += 0x7fffu + ((i >> 16) & 1u);
  return (unsigned short)(i >> 16);
}

__device__ __forceinline__ unsigned int blend_pack(unsigned int u0, unsigned int u1, float t){
  float a0 = __uint_as_float(u0 << 16);
  float a1 = __uint_as_float(u0 & 0xffff0000u);
  float b0 = __uint_as_float(u1 << 16);
  float b1 = __uint_as_float(u1 & 0xffff0000u);
  float r0 = fmaf(t, b0 - a0, a0);
  float r1 = fmaf(t, b1 - a1, a1);
  return (unsigned int)f2bf(r0) | (((unsigned int)f2bf(r1)) << 16);
}

__device__ __forceinline__ void async16(const void* g, void* l){
  __builtin_amdgcn_global_load_lds((const __attribute__((address_space(1))) void*)g,
                                   (__attribute__((address_space(3))) void*)l, 16, 0, 0);
}

// ---- merged prep: bid<4096 -> transpose+offset-conv partials (verified body);
//      bid>=4096 -> wmix (verified body). Saves one launch gap.
__global__ __launch_bounds__(256) void prep_kernel(const float* __restrict__ x,
    const float* __restrict__ w_off, const float* __restrict__ w_conv,
    unsigned short* __restrict__ atr, float* __restrict__ part,
    unsigned short* __restrict__ wm2){
  __shared__ float tile[64][67];
  __shared__ float wsh[64][9];
  __shared__ float red[4][64][3];
  int bid = blockIdx.x;
  if (bid < 4096){
    int bx = bid & 7, by = (bid >> 3) & 15, bz = bid >> 7;
    int b = bz, c0 = by * 64, t0 = bx * 64;
    int tx = threadIdx.x & 63, wy = threadIdx.x >> 6;
    const float* xp = x + ((size_t)b * NC + c0) * NT + t0;
    #pragma unroll
    for (int i = 0; i < 16; i++){ int cl = wy * 16 + i; tile[cl][1 + tx] = xp[(size_t)cl * NT + tx]; }
    if (threadIdx.x < 64){
      tile[tx][0]  = (t0 > 0)       ? xp[(size_t)tx * NT - 1]  : 0.f;
    } else if (threadIdx.x < 128){
      tile[tx][65] = (t0 + 64 < NT) ? xp[(size_t)tx * NT + 64] : 0.f;
    }
    for (int i = threadIdx.x; i < 576; i += 256){
      int c = i / 9, r = i % 9;
      wsh[c][r] = w_off[(size_t)(r / 3) * 3072 + (size_t)(c0 + c) * 3 + (r % 3)];
    }
    __syncthreads();
    int p = threadIdx.x & 31, r2 = threadIdx.x >> 5;
    unsigned int* dst = (unsigned int*)(atr + ((size_t)b * NT + t0) * NC + c0);
    #pragma unroll
    for (int i = 0; i < 8; i++){
      int tl = r2 * 8 + i;
      unsigned int lo = f2bf(tile[2 * p][1 + tl]);
      unsigned int hi = f2bf(tile[2 * p + 1][1 + tl]);
      dst[(size_t)tl * (NC / 2) + p] = lo | (hi << 16);
    }
    float s0 = 0.f, s1 = 0.f, s2 = 0.f;
    #pragma unroll 4
    for (int i = 0; i < 16; i++){
      int c = wy * 16 + i;
      float xm = tile[c][tx], xc = tile[c][1 + tx], xq = tile[c][2 + tx];
      s0 += xm * wsh[c][0] + xc * wsh[c][1] + xq * wsh[c][2];
      s1 += xm * wsh[c][3] + xc * wsh[c][4] + xq * wsh[c][5];
      s2 += xm * wsh[c][6] + xc * wsh[c][7] + xq * wsh[c][8];
    }
    red[wy][tx][0] = s0; red[wy][tx][1] = s1; red[wy][tx][2] = s2;
    __syncthreads();
    if (threadIdx.x < 192){
      int tl = threadIdx.x & 63, o = threadIdx.x >> 6;
      float v = red[0][tl][o] + red[1][tl][o] + red[2][tl][o] + red[3][tl][o];
      size_t m = (size_t)b * NT + t0 + tl;
      part[(m * 3 + o) * 16 + by] = v;
    }
  } else {
    int gid = (bid - 4096) * 256 + threadIdx.x;
    int o = gid >> 10, c = gid & 1023;
    const float ratio = (float)(1024.0 / 1023.0);
    float acc0 = 0.f, acc1 = 0.f, acc2 = 0.f;
    int wlo = (c > 2) ? c - 2 : 0;
    int whi = (c < 1021) ? c + 2 : 1023;
    for (int w = wlo; w <= whi; ++w){
      float px = (float)w * ratio - 0.5f;
      float x0 = floorf(px);
      float tx = px - x0;
      int i0 = (int)x0;
      int i0c = min(max(i0, 0), 1023);
      int i1c = min(max(i0 + 1, 0), 1023);
      float s = ((i0c == c) ? (1.0f - tx) : 0.f) + ((i1c == c) ? tx : 0.f);
      if (s != 0.f){
        const float* wc = w_conv + ((size_t)o * 1024 + w) * 3;
        acc0 += s * wc[0]; acc1 += s * wc[1]; acc2 += s * wc[2];
      }
    }
    size_t base = (size_t)o * 3072 + c;
    wm2[base]        = f2bf(acc0);
    wm2[base + 1024] = f2bf(acc1);
    wm2[base + 2048] = f2bf(acc2);
  }
}

// ---- blend + inlined index math (round-10, verified) ----
__global__ __launch_bounds__(256) void blend_kernel(
    const unsigned short* __restrict__ atr, const float* __restrict__ part,
    const float* __restrict__ b_off, unsigned short* __restrict__ Abl){
  __shared__ int si0[2][3], si1[2][3];
  __shared__ float sty[2][3];
  int row0 = blockIdx.x * 2;
  if (threadIdx.x < 6){
    int lr = (int)threadIdx.x / 3, o = (int)threadIdx.x % 3;
    int row = row0 + lr;
    int gid = row * 3 + o;
    const float* pp = part + (size_t)gid * 16;
    float p = b_off[o];
    #pragma unroll
    for (int i = 0; i < 16; i++) p += pp[i];
    int tt = row & 511;
    float base = (float)tt / 511.0f * 2.0f - 1.0f;
    float g = base + (float)(o - 1) * (float)(2.0 / 511.0) + p;
    g = fminf(1.0f, fmaxf(-1.0f, g));
    float py = ((g + 1.0f) * 512.0f - 1.0f) * 0.5f;
    float y0 = floorf(py);
    int i0 = (int)y0;
    si0[lr][o] = min(max(i0, 0), NT - 1);
    si1[lr][o] = min(max(i0 + 1, 0), NT - 1);
    sty[lr][o] = py - y0;
  }
  __syncthreads();
  int lr = threadIdx.x >> 7;
  int row = row0 + lr;
  int seg = threadIdx.x & 127;
  int b = row >> 9;
  const unsigned short* base = atr + (size_t)b * NT * NC;
  unsigned short* orow = Abl + (size_t)row * 3072 + (size_t)seg * 8;
  uint4 v0[3], v1[3]; float t[3];
  #pragma unroll
  for (int k = 0; k < 3; k++){
    v0[k] = *(const uint4*)(base + (size_t)si0[lr][k] * NC + (size_t)seg * 8);
    v1[k] = *(const uint4*)(base + (size_t)si1[lr][k] * NC + (size_t)seg * 8);
    t[k] = sty[lr][k];
  }
  #pragma unroll
  for (int k = 0; k < 3; k++){
    uint4 rv;
    rv.x = blend_pack(v0[k].x, v1[k].x, t[k]);
    rv.y = blend_pack(v0[k].y, v1[k].y, t[k]);
    rv.z = blend_pack(v0[k].z, v1[k].z, t[k]);
    rv.w = blend_pack(v0[k].w, v1[k].w, t[k]);
    *(uint4*)(orow + k * 1024) = rv;
  }
}

// ---- stage one 128x64 half-tile via global_load_lds, inverse-swizzled source ----
__device__ __forceinline__ void stage_half(const unsigned short* __restrict__ src,
                                           unsigned short* Lbase, int row0, int q,
                                           int w, int lane){
  int l3 = lane >> 3, l7 = lane & 7;
  int swc = ((l7 ^ l3) << 3);
  #pragma unroll
  for (int i = 0; i < 2; i++){
    int ci = i * 8 + w;
    const unsigned short* g = src + (size_t)(row0 + ci * 8 + l3) * 3072 + q * 64 + swc;
    async16(g, Lbase + ci * 512);
  }
}

// ---- 256x256 8-phase GEMM (round-3/7 loop, frozen) + LDS-coalesced epilogue ----
__global__ __launch_bounds__(512, 2) void gemm8_kernel(
    const unsigned short* __restrict__ A, const unsigned short* __restrict__ Bw,
    const float* __restrict__ b_conv, float* __restrict__ out){
  __shared__ __align__(16) unsigned short L[65536];

  int wg = blockIdx.x;
  int swz = (wg & 7) * 32 + (wg >> 3);
  int mtile = swz >> 2, ntile = swz & 3;
  int m0 = mtile * 256, n0 = ntile * 256;
  int tid = threadIdx.x, lane = tid & 63, w = tid >> 6;
  int wm_ = w >> 2, wn_ = w & 3;
  int lq = lane & 15, q4 = lane >> 4;
  int sl0 = (q4 ^ (lq & 7)) << 3;
  int sl1 = ((4 + q4) ^ (lq & 7)) << 3;
  int hb = wn_ >> 1, nb = (wn_ & 1) * 64;

  f32x4 acc[8][4];
  #pragma unroll
  for (int i = 0; i < 8; i++)
    #pragma unroll
    for (int j = 0; j < 4; j++) acc[i][j] = (f32x4){0.f, 0.f, 0.f, 0.f};

  // prologue: tile0 (A0,A1,B0,B1) + tile1 (B0,B1); vmcnt(4) drains tile0, leaves B(1)
  stage_half(A,  &L[0],                 m0,       0, w, lane);
  stage_half(A,  &L[8192],              m0 + 128, 0, w, lane);
  stage_half(Bw, &L[16384],             n0,       0, w, lane);
  stage_half(Bw, &L[16384 + 8192],      n0 + 128, 0, w, lane);
  stage_half(Bw, &L[32768 + 16384],        n0,       1, w, lane);
  stage_half(Bw, &L[32768 + 16384 + 8192], n0 + 128, 1, w, lane);
  asm volatile("s_waitcnt vmcnt(4)" ::: "memory");
  BAR;

  bf16x8 aA[4][2], bB[4][2];

  for (int t = 0; t < KTILES; ++t){
    int c = (t & 1) * 32768;
    int cn = ((t + 1) & 1) * 32768;
    const unsigned short* LA = &L[c + wm_ * 8192];
    const unsigned short* LB = &L[c + 16384 + hb * 8192];

    // ---- P1: read A(mh0) + B(nf0,1); stage A(t+1,h0); MFMA(mh0,np0)
    #pragma unroll
    for (int mf = 0; mf < 4; mf++){
      int r = mf * 16 + lq;
      aA[mf][0] = *(const bf16x8*)&LA[r * 64 + sl0];
      aA[mf][1] = *(const bf16x8*)&LA[r * 64 + sl1];
    }
    #pragma unroll
    for (int nf = 0; nf < 2; nf++){
      int r = nb + nf * 16 + lq;
      bB[nf][0] = *(const bf16x8*)&LB[r * 64 + sl0];
      bB[nf][1] = *(const bf16x8*)&LB[r * 64 + sl1];
    }
    if (t + 1 < KTILES) stage_half(A, &L[cn], m0, t + 1, w, lane);
    BAR; LGKM0;
    __builtin_amdgcn_s_setprio(1);
    #pragma unroll
    for (int mf = 0; mf < 4; mf++)
      #pragma unroll
      for (int nf = 0; nf < 2; nf++){
        acc[mf][nf] = __builtin_amdgcn_mfma_f32_16x16x32_bf16(aA[mf][0], bB[nf][0], acc[mf][nf], 0, 0, 0);
        acc[mf][nf] = __builtin_amdgcn_mfma_f32_16x16x32_bf16(aA[mf][1], bB[nf][1], acc[mf][nf], 0, 0, 0);
      }
    __builtin_amdgcn_s_setprio(0);
    BAR;

    // ---- P2: read B(nf2,3); stage A(t+1,h1); MFMA(mh0,np1)
    #pragma unroll
    for (int nf = 2; nf < 4; nf++){
      int r = nb + nf * 16 + lq;
      bB[nf][0] = *(const bf16x8*)&LB[r * 64 + sl0];
      bB[nf][1] = *(const bf16x8*)&LB[r * 64 + sl1];
    }
    if (t + 1 < KTILES) stage_half(A, &L[cn + 8192], m0 + 128, t + 1, w, lane);
    BAR; LGKM0;
    __builtin_amdgcn_s_setprio(1);
    #pragma unroll
    for (int mf = 0; mf < 4; mf++)
      #pragma unroll
      for (int nf = 2; nf < 4; nf++){
        acc[mf][nf] = __builtin_amdgcn_mfma_f32_16x16x32_bf16(aA[mf][0], bB[nf][0], acc[mf][nf], 0, 0, 0);
        acc[mf][nf] = __builtin_amdgcn_mfma_f32_16x16x32_bf16(aA[mf][1], bB[nf][1], acc[mf][nf], 0, 0, 0);
      }
    __builtin_amdgcn_s_setprio(0);
    BAR;

    // ---- P3: read A(mh1); stage B(t+2,h0); MFMA(mh1,np1)
    #pragma unroll
    for (int mf = 0; mf < 4; mf++){
      int r = 64 + mf * 16 + lq;
      aA[mf][0] = *(const bf16x8*)&LA[r * 64 + sl0];
      aA[mf][1] = *(const bf16x8*)&LA[r * 64 + sl1];
    }
    if (t + 2 < KTILES) stage_half(Bw, &L[c + 16384], n0, t + 2, w, lane);
    BAR; LGKM0;
    __builtin_amdgcn_s_setprio(1);
    #pragma unroll
    for (int mf = 0; mf < 4; mf++)
      #pragma unroll
      for (int nf = 2; nf < 4; nf++){
        acc[4 + mf][nf] = __builtin_amdgcn_mfma_f32_16x16x32_bf16(aA[mf][0], bB[nf][0], acc[4 + mf][nf], 0, 0, 0);
        acc[4 + mf][nf] = __builtin_amdgcn_mfma_f32_16x16x32_bf16(aA[mf][1], bB[nf][1], acc[4 + mf][nf], 0, 0, 0);
      }
    __builtin_amdgcn_s_setprio(0);
    BAR;

    // ---- P4: stage B(t+2,h1); MFMA(mh1,np0); boundary counted vmcnt
    if (t + 2 < KTILES) stage_half(Bw, &L[c + 16384 + 8192], n0 + 128, t + 2, w, lane);
    BAR;
    __builtin_amdgcn_s_setprio(1);
    #pragma unroll
    for (int mf = 0; mf < 4; mf++)
      #pragma unroll
      for (int nf = 0; nf < 2; nf++){
        acc[4 + mf][nf] = __builtin_amdgcn_mfma_f32_16x16x32_bf16(aA[mf][0], bB[nf][0], acc[4 + mf][nf], 0, 0, 0);
        acc[4 + mf][nf] = __builtin_amdgcn_mfma_f32_16x16x32_bf16(aA[mf][1], bB[nf][1], acc[4 + mf][nf], 0, 0, 0);
      }
    __builtin_amdgcn_s_setprio(0);
    if (t + 2 < KTILES)      { asm volatile("s_waitcnt vmcnt(4)" ::: "memory"); }
    else if (t + 1 < KTILES) { asm volatile("s_waitcnt vmcnt(0)" ::: "memory"); }
    BAR;
  }

  // ---- epilogue: LDS-coalesced store (per-wave [16][68] f32 tile, bias fused)
  {
    float* Lf = (float*)L;
    float* wt = Lf + w * 1088;
    float bcv[4];
    #pragma unroll
    for (int nf = 0; nf < 4; nf++) bcv[nf] = b_conv[n0 + wn_ * 64 + nf * 16 + lq];
    int ncol = n0 + wn_ * 64 + lq * 4;
    #pragma unroll
    for (int mh = 0; mh < 2; mh++)
      #pragma unroll
      for (int mf = 0; mf < 4; mf++){
        #pragma unroll
        for (int nf = 0; nf < 4; nf++){
          f32x4 v = acc[mh * 4 + mf][nf];
          #pragma unroll
          for (int j = 0; j < 4; j++)
            wt[(q4 * 4 + j) * 68 + nf * 16 + lq] = v[j] + bcv[nf];
        }
        LGKM0;
        int mrow0 = m0 + wm_ * 128 + mh * 64 + mf * 16;
        #pragma unroll
        for (int r = 0; r < 4; r++){
          f32x4 v = *(const f32x4*)&wt[(r * 4 + q4) * 68 + lq * 4];
          *(f32x4*)&out[(size_t)(mrow0 + r * 4 + q4) * NO + ncol] = v;
        }
        LGKM0;
      }
  }
}

extern "C" void kernel_launch(void* const* d_in, const int* in_sizes, int n_in,
                              void* d_out, int out_size, void* d_ws, size_t ws_size,
                              hipStream_t stream){
  (void)in_sizes; (void)n_in; (void)out_size; (void)ws_size;
  const float* x      = (const float*)d_in[0];
  const float* w_off  = (const float*)d_in[1];
  const float* b_off  = (const float*)d_in[2];
  const float* w_conv = (const float*)d_in[3];
  const float* b_conv = (const float*)d_in[4];
  float* out = (float*)d_out;

  char* ws = (char*)d_ws;
  unsigned short* atr = (unsigned short*)ws;                        // 32 MB  (B,T,C) bf16
  float* part = (float*)(ws + 33554432);                            // 3 MB
  unsigned short* wm2 = (unsigned short*)(ws + 37289984);           // 6 MB
  unsigned short* Abl = (unsigned short*)(ws + 43581440);           // 96 MB (proven layout)

  hipLaunchKernelGGL(prep_kernel,  dim3(8192), dim3(256), 0, stream,
                     x, w_off, w_conv, atr, part, wm2);
  hipLaunchKernelGGL(blend_kernel, dim3(16384 / 2), dim3(256), 0, stream,
                     atr, part, b_off, Abl);
  hipLaunchKernelGGL(gemm8_kernel, dim3((16384 / 256) * (1024 / 256)), dim3(512), 0, stream,
                     Abl, wm2, b_conv, out);
}